// Round 17
// baseline (70.134 us; speedup 1.0000x reference)
//
#include <hip/hip_runtime.h>

// out[b][i][j] = G[min(i,j)][max(i,j)], G[i][j] = sum_{i<=p<=q<=j} W[p][q],
// W[p][p]=D[p][p], W[p][q]=D[p][q]+D[q][p] (q>p), W=0 below diag;
// out[b][i][i-1]=D[b][i][i-1].
//
// k1: masked W tile, row-prefixed in registers (16-lane shfl segment scan),
//     stored bf16x2 into the RIGHT half-columns of the tile's own region in
//     d_out (race-free; dirty lines later overwritten by k4's G stores while
//     cached). Emits rowW, colWP (prefix-scanned), TS — fp32.
// k4: unpacks W~ (coalesced, issued early); wave-specialized preamble
//     (waves 0,2: rowOff; waves 1,3: colCar from colWP+TS); col-suffix in
//     registers; nontemporal final G stores (upper direct, lower via LDS
//     transpose); subdiagonal patched inline.
// Persistent grids: 176 WGs/batch, each handling exactly 3 tiles of one
// XCD band (66 = 22*3) -> zero tail rounds, producer/consumer XCD affinity.

#define NT 32
#define PD 65
#define NTRI 528

typedef float f32x4 __attribute__((ext_vector_type(4)));

__device__ __forceinline__ void tri_decode(int m, int& u, int& v) {
    int u_ = 0, rem = m;
    while (rem >= NT - u_) { rem -= NT - u_; ++u_; }
    u = u_;
    v = u_ + rem;
}

__device__ __forceinline__ unsigned pack_bf16(float lo, float hi) {
    unsigned a = __float_as_uint(lo), b = __float_as_uint(hi);
    unsigned ra = (a + 0x7FFFu + ((a >> 16) & 1u)) >> 16;   // RNE
    unsigned rb = (b + 0x7FFFu + ((b >> 16) & 1u)) >> 16;
    return ra | (rb << 16);
}

__global__ __launch_bounds__(256) void k1_w(const float* __restrict__ D,
                                            float* __restrict__ Mout,
                                            float* __restrict__ rowW,
                                            float* __restrict__ colWP,
                                            float* __restrict__ TS, int n) {
    const int x = blockIdx.x;                 // 0..175
    const int band = x & 7, slot = x >> 3;    // 22 slots per band
    const int b = blockIdx.y;
    const size_t nn = (size_t)n * n;
    const float* Db = D + (size_t)b * nn;
    float* Mb = Mout + (size_t)b * nn;
    __shared__ float Tl[64 * PD];
    __shared__ float s1[64];
    __shared__ float s2[4 * 64];
    const int t = threadIdx.x;
    const int c4 = (t & 15) * 4, r0 = t >> 4;

    for (int j = 0; j < 3; ++j) {
        const int m0 = band * 66 + slot + j * 22;
        int u, v;
        tri_decode(m0, u, v);
        const int i0 = u * 64, q0 = v * 64;
        const bool dg = (u == v);
        float4 va[4], vb[4];
#pragma unroll
        for (int m = 0; m < 4; ++m)
            va[m] = *(const float4*)&Db[(size_t)(i0 + r0 + 16 * m) * n + q0 + c4];
        if (!dg) {
#pragma unroll
            for (int m = 0; m < 4; ++m)
                vb[m] = *(const float4*)&Db[(size_t)(q0 + r0 + 16 * m) * n + i0 + c4];
        } else {
#pragma unroll
            for (int m = 0; m < 4; ++m) vb[m] = va[m];
        }
#pragma unroll
        for (int m = 0; m < 4; ++m) {
            const int rr = r0 + 16 * m;
            Tl[rr * PD + c4 + 0] = vb[m].x;
            Tl[rr * PD + c4 + 1] = vb[m].y;
            Tl[rr * PD + c4 + 2] = vb[m].z;
            Tl[rr * PD + c4 + 3] = vb[m].w;
        }
        __syncthreads();
        const int lg = t & 15;
        float cs0 = 0.f, cs1 = 0.f, cs2 = 0.f, cs3 = 0.f;
#pragma unroll
        for (int m = 0; m < 4; ++m) {
            const int r = r0 + 16 * m;
            float w0 = va[m].x + Tl[(c4 + 0) * PD + r];
            float w1 = va[m].y + Tl[(c4 + 1) * PD + r];
            float w2 = va[m].z + Tl[(c4 + 2) * PD + r];
            float w3 = va[m].w + Tl[(c4 + 3) * PD + r];
            if (dg) {
                w0 = (c4 + 0 > r) ? w0 : ((c4 + 0 == r) ? va[m].x : 0.f);
                w1 = (c4 + 1 > r) ? w1 : ((c4 + 1 == r) ? va[m].y : 0.f);
                w2 = (c4 + 2 > r) ? w2 : ((c4 + 2 == r) ? va[m].z : 0.f);
                w3 = (c4 + 3 > r) ? w3 : ((c4 + 3 == r) ? va[m].w : 0.f);
            }
            cs0 += w0; cs1 += w1; cs2 += w2; cs3 += w3;
            // in-register row prefix (4 elems) + 16-lane segment scan => 64 prefix
            const float p0 = w0, p1 = p0 + w1, p2 = p1 + w2, p3 = p2 + w3;
            const float totseg = p3;
            float incl = totseg;
#pragma unroll
            for (int d = 1; d < 16; d <<= 1) {
                const float sh = __shfl_up(incl, d, 16);
                if (lg >= d) incl += sh;
            }
            const float base = incl - totseg;
            uint2 pw;
            pw.x = pack_bf16(p0 + base, p1 + base);
            pw.y = pack_bf16(p2 + base, p3 + base);
            *(uint2*)&Mb[(size_t)(i0 + r) * n + q0 + 32 + (c4 >> 1)] = pw;
            if (lg == 15) s1[r] = incl;  // full (masked) row sum, fp32
        }
        cs0 += __shfl_xor(cs0, 16, 64); cs0 += __shfl_xor(cs0, 32, 64);
        cs1 += __shfl_xor(cs1, 16, 64); cs1 += __shfl_xor(cs1, 32, 64);
        cs2 += __shfl_xor(cs2, 16, 64); cs2 += __shfl_xor(cs2, 32, 64);
        cs3 += __shfl_xor(cs3, 16, 64); cs3 += __shfl_xor(cs3, 32, 64);
        const int wv_ = t >> 6, l = t & 63;
        if (l < 16) {
            s2[wv_ * 64 + 4 * l + 0] = cs0;
            s2[wv_ * 64 + 4 * l + 1] = cs1;
            s2[wv_ * 64 + 4 * l + 2] = cs2;
            s2[wv_ * 64 + 4 * l + 3] = cs3;
        }
        __syncthreads();
        if (t < 64) {
            rowW[((size_t)b * NT + v) * n + i0 + t] = s1[t];
            float cw = s2[t] + s2[64 + t] + s2[128 + t] + s2[192 + t];
#pragma unroll
            for (int d = 1; d < 64; d <<= 1) {
                const float sh = __shfl_up(cw, d, 64);
                if (t >= d) cw += sh;
            }
            colWP[((size_t)b * NT + u) * n + q0 + t] = cw;
            if (t == 63) TS[((size_t)b * NT + u) * NT + v] = cw;  // tile total
        }
    }
}

__global__ __launch_bounds__(256) void k4_tile(const float* __restrict__ D,
                                               float* __restrict__ out,
                                               const float* __restrict__ rowW,
                                               const float* __restrict__ colWP,
                                               const float* __restrict__ TS, int n) {
    const int x = blockIdx.x;
    const int band = x & 7, slot = x >> 3;
    const int b = blockIdx.y;
    const size_t nn = (size_t)n * n;
    const float* Db = D + (size_t)b * nn;
    float* Ob = out + (size_t)b * nn;
    __shared__ float Al[64 * PD];   // G^T: Al[c*PD+r] = G[r][c]
    __shared__ float st2[4 * 64];
    __shared__ float rOlA[64], rOlB[64], cClA[64], cClB[64];
    const int t = threadIdx.x;
    const int w = t >> 6, l = t & 63;
    const int s = w, lp = l;

    for (int j = 0; j < 3; ++j) {
        const int m0 = band * 66 + slot + j * 22;
        int bi, bq;
        tri_decode(m0, bi, bq);
        const int i0 = bi * 64, q0 = bq * 64;
        const bool dg = (bi == bq);
        // W~ tile reads (bf16-packed, right half): issued before preamble
        float wt[16];
#pragma unroll
        for (int k = 0; k < 16; ++k) {
            const unsigned wrd =
                __float_as_uint(Ob[(size_t)(i0 + 16 * s + k) * n + q0 + 32 + (lp >> 1)]);
            wt[k] = __uint_as_float((lp & 1) ? (wrd & 0xFFFF0000u) : (wrd << 16));
        }
        // wave-specialized preamble: pure sums, no dependent scan chains
        if ((w & 1) == 0) {
            float acc = 0.f;
            for (int v2 = bi + (w >> 1); v2 < bq; v2 += 2)
                acc += rowW[((size_t)b * NT + v2) * n + i0 + l];
            (w == 0 ? rOlA : rOlB)[l] = acc;
        } else {
            const int base = bi + 1 + ((w - 1) >> 1);  // w1: bi+1, w3: bi+2
            float acc = 0.f, tacc = 0.f;
            for (int bip = base; bip <= bq; bip += 2) {
                acc += colWP[((size_t)b * NT + bip) * n + q0 + l];
                const int v2 = bip + l;              // tos[bip][bq] spread over lanes
                if (v2 < bq) tacc += TS[((size_t)b * NT + bip) * NT + v2];
            }
            tacc += __shfl_xor(tacc, 1, 64);
            tacc += __shfl_xor(tacc, 2, 64);
            tacc += __shfl_xor(tacc, 4, 64);
            tacc += __shfl_xor(tacc, 8, 64);
            tacc += __shfl_xor(tacc, 16, 64);
            tacc += __shfl_xor(tacc, 32, 64);
            (w == 1 ? cClA : cClB)[l] = acc + tacc;
        }
        __syncthreads();
        // col suffix over register column fragment (rows 16s..16s+15 of col lp)
        float g[16];
#pragma unroll
        for (int k = 0; k < 16; ++k) {
            const int r = 16 * s + k;
            g[k] = wt[k] + rOlA[r] + rOlB[r];
        }
#pragma unroll
        for (int k = 14; k >= 0; --k) g[k] += g[k + 1];
        st2[s * 64 + lp] = g[0];
        __syncthreads();
        float off = cClA[lp] + cClB[lp];
        if (s < 1) off += st2[64 + lp];
        if (s < 2) off += st2[128 + lp];
        if (s < 3) off += st2[192 + lp];
        if (!dg) {
            // direct upper stores (coalesced per row, nontemporal) + G^T to LDS
#pragma unroll
            for (int k = 0; k < 16; ++k) {
                const float gv = g[k] + off;
                __builtin_nontemporal_store(gv,
                    &Ob[(size_t)(i0 + 16 * s + k) * n + q0 + lp]);
                Al[lp * PD + 16 * s + k] = gv;
            }
            __syncthreads();
            const int c4 = (t & 15) * 4, r0 = t >> 4;
#pragma unroll
            for (int m = 0; m < 4; ++m) {
                const int r = r0 + 16 * m;
                f32x4 l4;
                l4.x = Al[r * PD + c4 + 0];
                l4.y = Al[r * PD + c4 + 1];
                l4.z = Al[r * PD + c4 + 2];
                l4.w = Al[r * PD + c4 + 3];
                // boundary subdiagonal element out[q0][q0-1]: tile (bi, bi+1)
                if (bq == bi + 1 && r == 0 && c4 == 60)
                    l4.w = Db[(size_t)q0 * n + (q0 - 1)];
                __builtin_nontemporal_store(l4,
                    (f32x4*)&Ob[(size_t)(q0 + r) * n + i0 + c4]);
            }
        } else {
#pragma unroll
            for (int k = 0; k < 16; ++k) Al[lp * PD + 16 * s + k] = g[k] + off;
            __syncthreads();
#pragma unroll
            for (int m = 0; m < 16; ++m) {
                const int idx = 256 * m + t;
                const int rr = idx >> 6, cc = idx & 63;
                float val = (cc >= rr) ? Al[cc * PD + rr] : Al[rr * PD + cc];
                if (cc == rr - 1) val = Db[(size_t)(i0 + rr) * n + (i0 + cc)];
                __builtin_nontemporal_store(val,
                    &Ob[(size_t)(i0 + rr) * n + q0 + cc]);
            }
        }
        __syncthreads();   // region reuse guard before next tile's writes
    }
}

extern "C" void kernel_launch(void* const* d_in, const int* in_sizes, int n_in,
                              void* d_out, int out_size, void* d_ws, size_t ws_size,
                              hipStream_t stream) {
    const float* D = (const float*)d_in[0];
    float* out = (float*)d_out;
    const int n = 2048;
    const int B = in_sizes[0] / (n * n);

    float* ws = (float*)d_ws;
    const size_t szC = (size_t)B * NT * n;
    float* rowW  = ws;
    float* colWP = rowW + szC;
    float* TS    = colWP + szC;

    k1_w<<<dim3(176, B), dim3(256), 0, stream>>>(D, out, rowW, colWP, TS, n);
    k4_tile<<<dim3(176, B), dim3(256), 0, stream>>>(D, out, rowW, colWP, TS, n);
}

// Round 18
// 60.575 us; speedup vs baseline: 1.1578x; 1.1578x over previous
//
#include <hip/hip_runtime.h>

// out[b][i][j] = G[min(i,j)][max(i,j)], G[i][j] = sum_{i<=p<=q<=j} W[p][q],
// W[p][p]=D[p][p], W[p][q]=D[p][q]+D[q][p] (q>p), W=0 below diag;
// out[b][i][i-1]=D[b][i][i-1].
//
// k1 (528 upper tiles/batch): masked W tile, row-prefixed in registers (16-lane
//     shfl segment scan), stored bf16x2 into the RIGHT half-columns of the tile's
//     own region in d_out (race-free vs all G writes; dirty lines overwritten by
//     k4's G stores while cached). Emits rowW, colWP (prefix-scanned), TS (fp32).
// k4 (528 tiles): unpacks W~ (coalesced, issued early); wave-specialized preamble
//     (waves 0,2: rowOff; waves 1,3: colCar from colWP+TS); col-suffix in
//     registers; nontemporal final G stores (upper direct, lower via LDS
//     transpose). Subdiagonal patched inline.
// Both kernels use the same XCD-contiguous tile swizzle (528 = 8*66) so each
// XCD owns a contiguous tile band and k1-producer/k4-consumer share an XCD L2.

#define NT 32
#define PD 65
#define NTRI 528

typedef float f32x4 __attribute__((ext_vector_type(4)));

__device__ __forceinline__ void tri_decode(int m, int& u, int& v) {
    int u_ = 0, rem = m;
    while (rem >= NT - u_) { rem -= NT - u_; ++u_; }
    u = u_;
    v = u_ + rem;
}

__device__ __forceinline__ unsigned pack_bf16(float lo, float hi) {
    unsigned a = __float_as_uint(lo), b = __float_as_uint(hi);
    unsigned ra = (a + 0x7FFFu + ((a >> 16) & 1u)) >> 16;   // RNE
    unsigned rb = (b + 0x7FFFu + ((b >> 16) & 1u)) >> 16;
    return ra | (rb << 16);
}

__global__ __launch_bounds__(256) void k1_w(const float* __restrict__ D,
                                            float* __restrict__ Mout,
                                            float* __restrict__ rowW,
                                            float* __restrict__ colWP,
                                            float* __restrict__ TS, int n) {
    const int bid = blockIdx.x;
    const int m0 = (bid & 7) * 66 + (bid >> 3);   // XCD-contiguous bands
    int u, v;
    tri_decode(m0, u, v);
    const int b = blockIdx.y;
    const size_t nn = (size_t)n * n;
    const float* Db = D + (size_t)b * nn;
    float* Mb = Mout + (size_t)b * nn;
    __shared__ float Tl[64 * PD];
    __shared__ float s1[64];
    __shared__ float s2[4 * 64];
    const int t = threadIdx.x;
    const int c4 = (t & 15) * 4, r0 = t >> 4;
    const int i0 = u * 64, q0 = v * 64;
    const bool dg = (u == v);
    float4 va[4], vb[4];
#pragma unroll
    for (int m = 0; m < 4; ++m)
        va[m] = *(const float4*)&Db[(size_t)(i0 + r0 + 16 * m) * n + q0 + c4];
    if (!dg) {
#pragma unroll
        for (int m = 0; m < 4; ++m)
            vb[m] = *(const float4*)&Db[(size_t)(q0 + r0 + 16 * m) * n + i0 + c4];
    } else {
#pragma unroll
        for (int m = 0; m < 4; ++m) vb[m] = va[m];
    }
#pragma unroll
    for (int m = 0; m < 4; ++m) {
        const int rr = r0 + 16 * m;
        Tl[rr * PD + c4 + 0] = vb[m].x;
        Tl[rr * PD + c4 + 1] = vb[m].y;
        Tl[rr * PD + c4 + 2] = vb[m].z;
        Tl[rr * PD + c4 + 3] = vb[m].w;
    }
    __syncthreads();
    const int lg = t & 15;
    float cs0 = 0.f, cs1 = 0.f, cs2 = 0.f, cs3 = 0.f;
#pragma unroll
    for (int m = 0; m < 4; ++m) {
        const int r = r0 + 16 * m;
        float w0 = va[m].x + Tl[(c4 + 0) * PD + r];
        float w1 = va[m].y + Tl[(c4 + 1) * PD + r];
        float w2 = va[m].z + Tl[(c4 + 2) * PD + r];
        float w3 = va[m].w + Tl[(c4 + 3) * PD + r];
        if (dg) {
            w0 = (c4 + 0 > r) ? w0 : ((c4 + 0 == r) ? va[m].x : 0.f);
            w1 = (c4 + 1 > r) ? w1 : ((c4 + 1 == r) ? va[m].y : 0.f);
            w2 = (c4 + 2 > r) ? w2 : ((c4 + 2 == r) ? va[m].z : 0.f);
            w3 = (c4 + 3 > r) ? w3 : ((c4 + 3 == r) ? va[m].w : 0.f);
        }
        cs0 += w0; cs1 += w1; cs2 += w2; cs3 += w3;
        // in-register row prefix (4 elems) + 16-lane segment scan => full 64 prefix
        const float p0 = w0, p1 = p0 + w1, p2 = p1 + w2, p3 = p2 + w3;
        const float totseg = p3;
        float incl = totseg;
#pragma unroll
        for (int d = 1; d < 16; d <<= 1) {
            const float sh = __shfl_up(incl, d, 16);
            if (lg >= d) incl += sh;
        }
        const float base = incl - totseg;
        // pack W~ row-prefix values to bf16x2; RIGHT half of the tile's region
        uint2 pw;
        pw.x = pack_bf16(p0 + base, p1 + base);
        pw.y = pack_bf16(p2 + base, p3 + base);
        *(uint2*)&Mb[(size_t)(i0 + r) * n + q0 + 32 + (c4 >> 1)] = pw;
        if (lg == 15) s1[r] = incl;  // full (masked) row sum, fp32
    }
    cs0 += __shfl_xor(cs0, 16, 64); cs0 += __shfl_xor(cs0, 32, 64);
    cs1 += __shfl_xor(cs1, 16, 64); cs1 += __shfl_xor(cs1, 32, 64);
    cs2 += __shfl_xor(cs2, 16, 64); cs2 += __shfl_xor(cs2, 32, 64);
    cs3 += __shfl_xor(cs3, 16, 64); cs3 += __shfl_xor(cs3, 32, 64);
    const int wv_ = t >> 6, l = t & 63;
    if (l < 16) {
        s2[wv_ * 64 + 4 * l + 0] = cs0;
        s2[wv_ * 64 + 4 * l + 1] = cs1;
        s2[wv_ * 64 + 4 * l + 2] = cs2;
        s2[wv_ * 64 + 4 * l + 3] = cs3;
    }
    __syncthreads();
    if (t < 64) {
        rowW[((size_t)b * NT + v) * n + i0 + t] = s1[t];
        float cw = s2[t] + s2[64 + t] + s2[128 + t] + s2[192 + t];
        // inclusive prefix scan over the 64 columns
#pragma unroll
        for (int d = 1; d < 64; d <<= 1) {
            const float sh = __shfl_up(cw, d, 64);
            if (t >= d) cw += sh;
        }
        colWP[((size_t)b * NT + u) * n + q0 + t] = cw;
        if (t == 63) TS[((size_t)b * NT + u) * NT + v] = cw;  // tile total
    }
}

__global__ __launch_bounds__(256) void k4_tile(const float* __restrict__ D,
                                               float* __restrict__ out,
                                               const float* __restrict__ rowW,
                                               const float* __restrict__ colWP,
                                               const float* __restrict__ TS, int n) {
    const int bid = blockIdx.x;
    const int m0 = (bid & 7) * 66 + (bid >> 3);   // same XCD bands as k1
    int bi, bq;
    tri_decode(m0, bi, bq);
    const int b = blockIdx.y;
    const int i0 = bi * 64, q0 = bq * 64;
    const bool dg = (bi == bq);
    const size_t nn = (size_t)n * n;
    const float* Db = D + (size_t)b * nn;
    float* Ob = out + (size_t)b * nn;
    __shared__ float Al[64 * PD];   // G^T: Al[c*PD+r] = G[r][c]
    __shared__ float st2[4 * 64];
    __shared__ float rOlA[64], rOlB[64], cClA[64], cClB[64];
    const int t = threadIdx.x;
    const int w = t >> 6, l = t & 63;
    const int s = w, lp = l;
    // W~ tile reads (bf16-packed, right half): issued before preamble
    float wt[16];
#pragma unroll
    for (int k = 0; k < 16; ++k) {
        const unsigned wrd =
            __float_as_uint(Ob[(size_t)(i0 + 16 * s + k) * n + q0 + 32 + (lp >> 1)]);
        wt[k] = __uint_as_float((lp & 1) ? (wrd & 0xFFFF0000u) : (wrd << 16));
    }
    // wave-specialized preamble: pure sums, no dependent scan chains
    if ((w & 1) == 0) {
        float acc = 0.f;
        for (int v2 = bi + (w >> 1); v2 < bq; v2 += 2)
            acc += rowW[((size_t)b * NT + v2) * n + i0 + l];
        (w == 0 ? rOlA : rOlB)[l] = acc;
    } else {
        const int base = bi + 1 + ((w - 1) >> 1);  // w1: bi+1, w3: bi+2
        float acc = 0.f, tacc = 0.f;
        for (int bip = base; bip <= bq; bip += 2) {
            acc += colWP[((size_t)b * NT + bip) * n + q0 + l];
            const int v2 = bip + l;              // tos[bip][bq] spread over lanes
            if (v2 < bq) tacc += TS[((size_t)b * NT + bip) * NT + v2];
        }
        tacc += __shfl_xor(tacc, 1, 64);
        tacc += __shfl_xor(tacc, 2, 64);
        tacc += __shfl_xor(tacc, 4, 64);
        tacc += __shfl_xor(tacc, 8, 64);
        tacc += __shfl_xor(tacc, 16, 64);
        tacc += __shfl_xor(tacc, 32, 64);
        (w == 1 ? cClA : cClB)[l] = acc + tacc;
    }
    __syncthreads();
    // col suffix over register column fragment (rows 16s..16s+15 of col lp)
    float g[16];
#pragma unroll
    for (int k = 0; k < 16; ++k) {
        const int r = 16 * s + k;
        g[k] = wt[k] + rOlA[r] + rOlB[r];
    }
#pragma unroll
    for (int k = 14; k >= 0; --k) g[k] += g[k + 1];
    st2[s * 64 + lp] = g[0];
    __syncthreads();
    float off = cClA[lp] + cClB[lp];
    if (s < 1) off += st2[64 + lp];
    if (s < 2) off += st2[128 + lp];
    if (s < 3) off += st2[192 + lp];
    if (!dg) {
        // direct upper stores (coalesced per row, nontemporal) + G^T to LDS
#pragma unroll
        for (int k = 0; k < 16; ++k) {
            const float gv = g[k] + off;
            __builtin_nontemporal_store(gv, &Ob[(size_t)(i0 + 16 * s + k) * n + q0 + lp]);
            Al[lp * PD + 16 * s + k] = gv;
        }
        __syncthreads();
        const int c4 = (t & 15) * 4, r0 = t >> 4;
#pragma unroll
        for (int m = 0; m < 4; ++m) {
            const int r = r0 + 16 * m;
            f32x4 l4;
            l4.x = Al[r * PD + c4 + 0];
            l4.y = Al[r * PD + c4 + 1];
            l4.z = Al[r * PD + c4 + 2];
            l4.w = Al[r * PD + c4 + 3];
            // boundary subdiagonal element out[q0][q0-1] lives in tile (bi, bi+1)
            if (bq == bi + 1 && r == 0 && c4 == 60) l4.w = Db[(size_t)q0 * n + (q0 - 1)];
            __builtin_nontemporal_store(l4, (f32x4*)&Ob[(size_t)(q0 + r) * n + i0 + c4]);
        }
    } else {
#pragma unroll
        for (int k = 0; k < 16; ++k) Al[lp * PD + 16 * s + k] = g[k] + off;
        __syncthreads();
#pragma unroll
        for (int m = 0; m < 16; ++m) {
            const int idx = 256 * m + t;
            const int rr = idx >> 6, cc = idx & 63;
            float val = (cc >= rr) ? Al[cc * PD + rr] : Al[rr * PD + cc];
            if (cc == rr - 1) val = Db[(size_t)(i0 + rr) * n + (i0 + cc)];
            __builtin_nontemporal_store(val, &Ob[(size_t)(i0 + rr) * n + q0 + cc]);
        }
    }
}

extern "C" void kernel_launch(void* const* d_in, const int* in_sizes, int n_in,
                              void* d_out, int out_size, void* d_ws, size_t ws_size,
                              hipStream_t stream) {
    const float* D = (const float*)d_in[0];
    float* out = (float*)d_out;
    const int n = 2048;
    const int B = in_sizes[0] / (n * n);

    float* ws = (float*)d_ws;
    const size_t szC = (size_t)B * NT * n;
    float* rowW  = ws;
    float* colWP = rowW + szC;
    float* TS    = colWP + szC;

    k1_w<<<dim3(NTRI, B), dim3(256), 0, stream>>>(D, out, rowW, colWP, TS, n);
    k4_tile<<<dim3(NTRI, B), dim3(256), 0, stream>>>(D, out, rowW, colWP, TS, n);
}